// Round 7
// baseline (183.155 us; speedup 1.0000x reference)
//
#include <hip/hip_runtime.h>

// LSTM: B=4096, T=256, I=8, H=32, O=1, fp32 in/out, bf16 MFMA compute.
// R12 = R11/R7 skeleton with TWO independent 16-row tiles interleaved per
// block: 128 blocks x 8 waves, one barrier serves BOTH tiles' steps.
// Rationale: R7/R11's 700 cyc/step = ~400 serial chain (ds_read 120 + MFMA
// + act-dep ~110 + barrier ~100) + ~136 issue. The chain is per-tile; two
// tiles in the same waves overlap chains via ILP and amortize the barrier:
// predicted ~320 cyc/step. R8 (2 blocks/CU) failed from scheduler
// contention + duplicated lanes — this keeps R7's exact wave shape
// (8 waves, 2/SIMD, 1 block/CU) and issue load per step.
// Per tile (unchanged from R7): wave w owns hidden j = 4w + q via weight-row
// permutation fr -> n = 32*(fr&3) + 4w + (fr>>2) (weights are the MFMA FIRST
// operand); lane (q,L) accum reg r = gate r at (m=L, j=4w+q); c/h update
// in-register, 8 trans/lane/step/tile. x staged in LDS as bf16 in two
// 128-step chunks per tile (zero global ops in the steady loop). Gate-g
// rows pre-scaled by 2*log2e (others log2e): 5 exp2 + 3 rcp per value.

#define T_LEN   256
#define HALF_T  128
#define XSTRIDE 130   // shorts per timestep row (16 L x 8 bf16 + 2 pad)
#define LOG2E   1.4426950408889634f

typedef short bf16x8 __attribute__((ext_vector_type(8)));
typedef float f32x4  __attribute__((ext_vector_type(4)));
typedef unsigned u32x4 __attribute__((ext_vector_type(4)));

static __device__ inline short f2bf_rne(float f) {          // one-time (weights)
    union { float f; unsigned u; } v; v.f = f;
    unsigned u = v.u;
    return (short)((u + 0x7FFFu + ((u >> 16) & 1u)) >> 16);
}
static __device__ inline short f2bf_fast(float f) {         // round-half-up
    union { float f; unsigned u; } v; v.f = f;
    return (short)((v.u + 0x8000u) >> 16);
}
static __device__ inline unsigned pack_bf2(float a, float b) {  // low=a, high=b
    union { float f; unsigned u; } x, y; x.f = a; y.f = b;
    return ((x.u + 0x8000u) >> 16) | ((y.u + 0x8000u) & 0xFFFF0000u);
}
static __device__ inline float bf2f(short s) {
    union { unsigned u; float f; } v;
    v.u = ((unsigned)(unsigned short)s) << 16;
    return v.f;
}

__global__ __launch_bounds__(512, 2) void lstm_kernel(
    const float* __restrict__ x, const float* __restrict__ W_ih,
    const float* __restrict__ W_hh, const float* __restrict__ b_ih,
    const float* __restrict__ b_hh, const float* __restrict__ W_out,
    const float* __restrict__ b_out, float* __restrict__ out)
{
    // Per tile: x chunk [t_local(0..127)][L(0..15)][8] bf16 (conflict-free)
    // + h double buffer [buf][m(0..15)][k(0..31)] bf16, row stride 40.
    __shared__ __attribute__((aligned(16))) short xlA[HALF_T * XSTRIDE];  // 32.5 KB
    __shared__ __attribute__((aligned(16))) short xlB[HALF_T * XSTRIDE];  // 32.5 KB
    __shared__ __attribute__((aligned(16))) short hA[2][16 * 40];         // 2.5 KB
    __shared__ __attribute__((aligned(16))) short hB[2][16 * 40];         // 2.5 KB

    const int tid  = threadIdx.x;
    const int w    = tid >> 6;        // wave 0..7 -> owns j = 4w + q
    const int lane = tid & 63;
    const int L    = lane & 15;       // batch row within tile / frag row
    const int q    = lane >> 4;       // quad
    const int row0 = blockIdx.x * 32; // tile A rows [row0,row0+16), B +16
    const float4* xv = (const float4*)x;

    // ---- one-time: weight fragments (FIRST-operand layout [row=L][k=8q+j]),
    // SHARED by both tiles. Row fr=L holds W row n = 32*(L&3)+4w+(L>>2);
    // gate = L&3, scaled by log2e (gate-g rows: 2*log2e folds tanh's 2).
    const int   n  = 32 * (L & 3) + 4 * w + (L >> 2);
    const float sc = ((L & 3) == 2 ? 2.f * LOG2E : LOG2E);
    bf16x8 whh_f, wih_f = (bf16x8){0,0,0,0,0,0,0,0};
    {
        const float* src = W_hh + n * 32 + q * 8;
#pragma unroll
        for (int j = 0; j < 8; ++j) whh_f[j] = f2bf_rne(src[j] * sc);
        if (q == 0) {                              // only k=0..7 exist (I=8)
            const float* s2 = W_ih + n * 8;
#pragma unroll
            for (int j = 0; j < 8; ++j) wih_f[j] = f2bf_rne(s2[j] * sc);
        }
    }
    // bias in C-layout: reg r -> row fr=4q+r -> n_r = 32r + 4w + q
    f32x4 bias;
#pragma unroll
    for (int r = 0; r < 4; ++r) {
        const int   nr = 32 * r + 4 * w + q;
        const float sr = (r == 2 ? 2.f * LOG2E : LOG2E);
        bias[r] = (b_ih[nr] + b_hh[nr]) * sr;
    }

    // zero h(0) buffers
    for (int i = tid; i < 16 * 40; i += 512) { hA[0][i] = 0; hB[0][i] = 0; }

    // ---- stage chunk 0 (t in [0,128)) for both tiles ----
    // idx = tid + 512*it: L2 = idx>>7, tl = idx&127; 32 B/lane coalesced.
#define STAGE_CHUNK(XL_, ROWB_, TOFF_)                                          \
    {                                                                           \
        _Pragma("unroll")                                                       \
        for (int it = 0; it < 4; ++it) {                                        \
            const int idx = tid + (it << 9);                                    \
            const int L2  = idx >> 7;                                           \
            const int tl  = idx & (HALF_T - 1);                                 \
            const float4* srcp = xv + ((size_t)((ROWB_) + L2) * T_LEN + (TOFF_) + tl) * 2; \
            const float4 a = srcp[0], b = srcp[1];                              \
            u32x4 u;                                                            \
            u[0] = pack_bf2(a.x, a.y); u[1] = pack_bf2(a.z, a.w);               \
            u[2] = pack_bf2(b.x, b.y); u[3] = pack_bf2(b.z, b.w);               \
            *(u32x4*)(&(XL_)[tl * XSTRIDE + L2 * 8]) = u;                       \
        }                                                                       \
    }
    STAGE_CHUNK(xlA, row0, 0)
    STAGE_CHUNK(xlB, row0 + 16, 0)
    __syncthreads();

    // zx(0) from x(0) for both tiles
    f32x4 zxA, zxB;
    {
        const bf16x8 xa = *(const bf16x8*)(&xlA[L * 8]);
        const bf16x8 xb = *(const bf16x8*)(&xlB[L * 8]);
        zxA = __builtin_amdgcn_mfma_f32_16x16x32_bf16(wih_f, xa, bias, 0, 0, 0);
        zxB = __builtin_amdgcn_mfma_f32_16x16x32_bf16(wih_f, xb, bias, 0, 0, 0);
    }

    float cA = 0.f, cB = 0.f;
    const int hw_off = 4 * w + q;      // this lane's j

    // act: regs r = (i, f, g2, o); g rows pre-doubled.
    // sig(a)*tanh(b) = (1-eb)*rcp((1+ea)(1+eb)); only c-exp clamped.
#define ACT(ACC_, C_, HV_)                                                      \
        const float ei##HV_ = __builtin_amdgcn_exp2f(-(ACC_)[0]);               \
        const float ef##HV_ = __builtin_amdgcn_exp2f(-(ACC_)[1]);               \
        const float eg##HV_ = __builtin_amdgcn_exp2f(-(ACC_)[2]);               \
        const float eo##HV_ = __builtin_amdgcn_exp2f(-(ACC_)[3]);               \
        const float fv##HV_ = __builtin_amdgcn_rcpf(1.f + ef##HV_);             \
        const float ig##HV_ = (1.f - eg##HV_) *                                 \
            __builtin_amdgcn_rcpf((1.f + ei##HV_) * (1.f + eg##HV_));           \
        C_ = fmaf(fv##HV_, C_, ig##HV_);                                        \
        const float ec##HV_ = __builtin_amdgcn_exp2f(fminf(C_ * (-2.f * LOG2E), 40.f)); \
        const float HV_ = (1.f - ec##HV_) *                                     \
            __builtin_amdgcn_rcpf((1.f + eo##HV_) * (1.f + ec##HV_));

    // One interval: both tiles advance one step, ONE barrier.
#define LSTM_STEP(T_, TN_)                                                      \
    {                                                                           \
        const int par = (T_) & 1, nxt = par ^ 1;                                \
        const bf16x8 hfA = *(const bf16x8*)(&hA[par][L * 40 + q * 8]);          \
        const bf16x8 hfB = *(const bf16x8*)(&hB[par][L * 40 + q * 8]);          \
        const bf16x8 xfA = *(const bf16x8*)(                                    \
            &xlA[((TN_) & (HALF_T - 1)) * XSTRIDE + L * 8]);                    \
        const bf16x8 xfB = *(const bf16x8*)(                                    \
            &xlB[((TN_) & (HALF_T - 1)) * XSTRIDE + L * 8]);                    \
        const f32x4 accA =                                                      \
            __builtin_amdgcn_mfma_f32_16x16x32_bf16(whh_f, hfA, zxA, 0, 0, 0);  \
        const f32x4 accB =                                                      \
            __builtin_amdgcn_mfma_f32_16x16x32_bf16(whh_f, hfB, zxB, 0, 0, 0);  \
        zxA = __builtin_amdgcn_mfma_f32_16x16x32_bf16(wih_f, xfA, bias, 0, 0, 0);\
        zxB = __builtin_amdgcn_mfma_f32_16x16x32_bf16(wih_f, xfB, bias, 0, 0, 0);\
        ACT(accA, cA, hvA_)                                                     \
        ACT(accB, cB, hvB_)                                                     \
        hA[nxt][L * 40 + hw_off] = f2bf_fast(hvA_);                             \
        hB[nxt][L * 40 + hw_off] = f2bf_fast(hvB_);                             \
        __syncthreads();                                                        \
    }

    // ---- first half: t = 0..126, xfrag slots 1..127 all in chunk 0 ----
#pragma unroll 2
    for (int t = 0; t < HALF_T - 1; ++t) LSTM_STEP(t, t + 1)

    // ---- restage chunk 1 (t in [128,256)); prior reads drained by the
    //      t=126 barrier ----
    STAGE_CHUNK(xlA, row0, HALF_T)
    STAGE_CHUNK(xlB, row0 + 16, HALF_T)
    __syncthreads();   // one-time vm drain; loop stays vm-free

    // ---- second half: t = 127..254, xfrag slots (t+1)&127 in chunk 1 ----
#pragma unroll 2
    for (int t = HALF_T - 1; t < T_LEN - 1; ++t) LSTM_STEP(t, t + 1)

    // ---- peeled t = 255: no xfrag/zx (dead), store h(T) into buf 0 ----
    {
        const int par = (T_LEN - 1) & 1, nxt = par ^ 1;   // 1 -> 0
        const bf16x8 hfA = *(const bf16x8*)(&hA[par][L * 40 + q * 8]);
        const bf16x8 hfB = *(const bf16x8*)(&hB[par][L * 40 + q * 8]);
        const f32x4 accA =
            __builtin_amdgcn_mfma_f32_16x16x32_bf16(whh_f, hfA, zxA, 0, 0, 0);
        const f32x4 accB =
            __builtin_amdgcn_mfma_f32_16x16x32_bf16(whh_f, hfB, zxB, 0, 0, 0);
        ACT(accA, cA, hvA_)
        ACT(accB, cB, hvB_)
        hA[nxt][L * 40 + hw_off] = f2bf_fast(hvA_);
        hB[nxt][L * 40 + hw_off] = f2bf_fast(hvB_);
        __syncthreads();
    }
#undef LSTM_STEP
#undef ACT
#undef STAGE_CHUNK

    // h(T) lives in buf[0] of each tile; rows row0+tid for tid<32.
    if (tid < 32) {
        const short* hp = (tid < 16 ? hA[0] : hB[0]) + (tid & 15) * 40;
        float s = b_out[0];
#pragma unroll
        for (int k = 0; k < 32; ++k) s = fmaf(bf2f(hp[k]), W_out[k], s);
        out[row0 + tid] = s;
    }
}

extern "C" void kernel_launch(void* const* d_in, const int* in_sizes, int n_in,
                              void* d_out, int out_size, void* d_ws, size_t ws_size,
                              hipStream_t stream) {
    const float* x     = (const float*)d_in[0];
    const float* W_ih  = (const float*)d_in[1];
    const float* W_hh  = (const float*)d_in[2];
    const float* b_ih  = (const float*)d_in[3];
    const float* b_hh  = (const float*)d_in[4];
    const float* W_out = (const float*)d_in[5];
    const float* b_out = (const float*)d_in[6];
    float* out = (float*)d_out;

    const int B = in_sizes[0] / (T_LEN * 8);  // 4096
    const int tiles = B / 32;                 // 128 blocks, two tiles each
    lstm_kernel<<<tiles, 512, 0, stream>>>(x, W_ih, W_hh, b_ih, b_hh, W_out, b_out, out);
}

// Round 8
// 141.438 us; speedup vs baseline: 1.2949x; 1.2949x over previous
//
#include <hip/hip_runtime.h>

// LSTM: B=4096, T=256, I=8, H=32, O=1, fp32 in/out, bf16 MFMA compute.
// R13 = R11 (best measured: 74.5 us, 700 cyc/step) + xfrag REGISTER
// PIPELINE: step t reads x(t+2)'s fragment into regs (issued right after
// hfrag, consumed next iteration), halving the post-barrier LDS burst from
// 16 to 8 ds_read_b128 per CU-step. Mechanism (from R12's +366 cyc/extra-
// tile): the CU-shared LDS unit serializes the post-barrier read burst at
// ~10-12 cyc/b128; the tail wave's MFMA (and hence the next barrier) eats
// the whole queue. xfrag's own ~120-cyc latency now hides under the act
// phase (lgkmcnt(1) lets the h-MFMA proceed; __syncthreads' lgkmcnt(0)
// lands after act). Restage boundary moves to after step 125 (step 126
// consumes reg-x(127), reads x(128) from fresh chunk 1).
// Structure log: R8 2 blocks/CU=950cyc/step (contention); R9 4-wave
// 2j/lane=775 (trans on-chain ~8-9cyc/instr); R10 global-x=1220 (HBM on-
// chain); R12 2 tiles/block=533/step-pair but half CUs idle -> 113us.
// 256 blocks (1/CU) x 8 waves; wave w owns j=4w+q via weight-row perm
// fr -> n = 32*(fr&3)+4w+(fr>>2) (weights = MFMA FIRST operand); lane (q,L)
// acc reg r = gate r at (m=L, j=4w+q); c/h in-register; 8 trans/lane/step.
// x staged in LDS bf16, two 128-step chunks; gate-g rows pre-scaled 2*log2e.

#define T_LEN   256
#define HALF_T  128
#define XSTRIDE 130   // shorts per timestep row (16 L x 8 bf16 + 2 pad)
#define LOG2E   1.4426950408889634f

typedef short bf16x8 __attribute__((ext_vector_type(8)));
typedef float f32x4  __attribute__((ext_vector_type(4)));
typedef unsigned u32x4 __attribute__((ext_vector_type(4)));

static __device__ inline short f2bf_rne(float f) {          // one-time (weights)
    union { float f; unsigned u; } v; v.f = f;
    unsigned u = v.u;
    return (short)((u + 0x7FFFu + ((u >> 16) & 1u)) >> 16);
}
static __device__ inline short f2bf_fast(float f) {         // round-half-up
    union { float f; unsigned u; } v; v.f = f;
    return (short)((v.u + 0x8000u) >> 16);
}
static __device__ inline unsigned pack_bf2(float a, float b) {  // low=a, high=b
    union { float f; unsigned u; } x, y; x.f = a; y.f = b;
    return ((x.u + 0x8000u) >> 16) | ((y.u + 0x8000u) & 0xFFFF0000u);
}
static __device__ inline float bf2f(short s) {
    union { unsigned u; float f; } v;
    v.u = ((unsigned)(unsigned short)s) << 16;
    return v.f;
}

__global__ __launch_bounds__(512, 2) void lstm_kernel(
    const float* __restrict__ x, const float* __restrict__ W_ih,
    const float* __restrict__ W_hh, const float* __restrict__ b_ih,
    const float* __restrict__ b_hh, const float* __restrict__ W_out,
    const float* __restrict__ b_out, float* __restrict__ out)
{
    // x chunk: [t_local(0..127)][L(0..15)][8] bf16 (conflict-free: dword
    // stride 65/t, 4/L; loop reads are 4-lane broadcasts of 16 addresses)
    __shared__ __attribute__((aligned(16))) short xl[HALF_T * XSTRIDE];
    // h double buffer: [buf][m(0..15)][k(0..31)] bf16, row stride 40 shorts
    __shared__ __attribute__((aligned(16))) short h_lds[2][16 * 40];

    const int tid  = threadIdx.x;
    const int w    = tid >> 6;        // wave 0..7 -> owns j = 4w + q
    const int lane = tid & 63;
    const int L    = lane & 15;       // batch row within tile / frag row
    const int q    = lane >> 4;       // quad
    const int row0 = blockIdx.x * 16;
    const float4* xv = (const float4*)x;

    // ---- one-time: weight fragments (FIRST-operand layout [row=L][k=8q+j]) ----
    // row fr=L holds W row n = 32*(L&3) + 4w + (L>>2); gate = L&3,
    // scaled by log2e (gate-g rows: 2*log2e, folding tanh's factor 2).
    const int   n  = 32 * (L & 3) + 4 * w + (L >> 2);
    const float sc = ((L & 3) == 2 ? 2.f * LOG2E : LOG2E);
    bf16x8 whh_f, wih_f = (bf16x8){0,0,0,0,0,0,0,0};
    {
        const float* src = W_hh + n * 32 + q * 8;
#pragma unroll
        for (int j = 0; j < 8; ++j) whh_f[j] = f2bf_rne(src[j] * sc);
        if (q == 0) {                              // only k=0..7 exist (I=8)
            const float* s2 = W_ih + n * 8;
#pragma unroll
            for (int j = 0; j < 8; ++j) wih_f[j] = f2bf_rne(s2[j] * sc);
        }
    }
    // bias in C-layout: reg r -> row fr=4q+r -> n_r = 32r + 4w + q
    f32x4 bias;
#pragma unroll
    for (int r = 0; r < 4; ++r) {
        const int   nr = 32 * r + 4 * w + q;
        const float sr = (r == 2 ? 2.f * LOG2E : LOG2E);
        bias[r] = (b_ih[nr] + b_hh[nr]) * sr;
    }

    // zero h(0) buffer
    for (int i = tid; i < 16 * 40; i += 512) h_lds[0][i] = 0;

    // ---- stage chunk 0 (t in [0,128)) into xl ----
    // idx = tid + 512*it: L2 = idx>>7, tl = idx&127; 32 B/lane coalesced.
#pragma unroll
    for (int it = 0; it < 4; ++it) {
        const int idx = tid + (it << 9);
        const int L2  = idx >> 7;
        const int tl  = idx & (HALF_T - 1);
        const float4* srcp = xv + ((size_t)(row0 + L2) * T_LEN + tl) * 2;
        const float4 a = srcp[0], b = srcp[1];
        u32x4 u;
        u[0] = pack_bf2(a.x, a.y); u[1] = pack_bf2(a.z, a.w);
        u[2] = pack_bf2(b.x, b.y); u[3] = pack_bf2(b.z, b.w);
        *(u32x4*)(&xl[tl * XSTRIDE + L2 * 8]) = u;
    }
    __syncthreads();

    // zx(0) from x(0); prime the x register pipeline with x(1)
    f32x4 zx;
    bf16x8 xcur;
    {
        const bf16x8 xf0 = *(const bf16x8*)(&xl[L * 8]);
        zx   = __builtin_amdgcn_mfma_f32_16x16x32_bf16(wih_f, xf0, bias, 0, 0, 0);
        xcur = *(const bf16x8*)(&xl[1 * XSTRIDE + L * 8]);     // x(1)
    }

    float c = 0.f;
    const int hw_off = 4 * w + q;      // this lane's j

    // One step: read h(t) (chain) + x(t+2)->regs (off-chain, consumed next
    // iter), MFMA, zx from reg-x(t+1), act, store h(t+1), barrier.
    // TN2_ = slot of x(t+2) in the current chunk.
#define LSTM_STEP(T_, TN2_)                                                     \
    {                                                                           \
        const int par = (T_) & 1, nxt = par ^ 1;                                \
        const bf16x8 hfrag = *(const bf16x8*)(&h_lds[par][L * 40 + q * 8]);     \
        const bf16x8 xnext = *(const bf16x8*)(                                  \
            &xl[((TN2_) & (HALF_T - 1)) * XSTRIDE + L * 8]);                    \
        const f32x4 acc =                                                       \
            __builtin_amdgcn_mfma_f32_16x16x32_bf16(whh_f, hfrag, zx, 0, 0, 0); \
        zx = __builtin_amdgcn_mfma_f32_16x16x32_bf16(wih_f, xcur, bias, 0, 0, 0);\
        const float ei = __builtin_amdgcn_exp2f(-acc[0]);                       \
        const float ef = __builtin_amdgcn_exp2f(-acc[1]);                       \
        const float eg = __builtin_amdgcn_exp2f(-acc[2]);                       \
        const float eo = __builtin_amdgcn_exp2f(-acc[3]);                       \
        const float fv = __builtin_amdgcn_rcpf(1.f + ef);                       \
        const float ig = (1.f - eg) * __builtin_amdgcn_rcpf((1.f + ei) * (1.f + eg)); \
        c = fmaf(fv, c, ig);                                                    \
        const float ec = __builtin_amdgcn_exp2f(fminf(c * (-2.f * LOG2E), 40.f));\
        const float hv = (1.f - ec) * __builtin_amdgcn_rcpf((1.f + eo) * (1.f + ec)); \
        h_lds[nxt][L * 40 + hw_off] = f2bf_fast(hv);                            \
        xcur = xnext;                                                           \
        __syncthreads();                                                        \
    }

    // ---- first phase: t = 0..125; x(t+2) slots 2..127 all in chunk 0 ----
#pragma unroll 2
    for (int t = 0; t < HALF_T - 2; ++t) LSTM_STEP(t, t + 2)

    // ---- restage chunk 1 (t in [128,256)). Step 125's reads completed at
    //      its __syncthreads (lgkmcnt(0) precedes s_barrier), so chunk 0 is
    //      dead; x(126),x(127) live in the register pipeline. ----
#pragma unroll
    for (int it = 0; it < 4; ++it) {
        const int idx = tid + (it << 9);
        const int L2  = idx >> 7;
        const int tl  = idx & (HALF_T - 1);
        const float4* srcp = xv + ((size_t)(row0 + L2) * T_LEN + HALF_T + tl) * 2;
        const float4 a = srcp[0], b = srcp[1];
        u32x4 u;
        u[0] = pack_bf2(a.x, a.y); u[1] = pack_bf2(a.z, a.w);
        u[2] = pack_bf2(b.x, b.y); u[3] = pack_bf2(b.z, b.w);
        *(u32x4*)(&xl[tl * XSTRIDE + L2 * 8]) = u;
    }
    __syncthreads();   // one-time vm drain; loop stays vm-free

    // ---- second phase: t = 126..254; x(t+2) slots (t+2)&127 in chunk 1,
    //      clamped at 255 (t=254 re-reads x(255), dead but harmless) ----
#pragma unroll 2
    for (int t = HALF_T - 2; t < T_LEN - 1; ++t)
        LSTM_STEP(t, (t + 2 > T_LEN - 1 ? T_LEN - 1 : t + 2))

    // ---- peeled t = 255: no xfrag/zx (dead), store h(T) into buf 0 ----
    {
        const int par = (T_LEN - 1) & 1, nxt = par ^ 1;   // 1 -> 0
        const bf16x8 hfrag = *(const bf16x8*)(&h_lds[par][L * 40 + q * 8]);
        const f32x4 acc =
            __builtin_amdgcn_mfma_f32_16x16x32_bf16(whh_f, hfrag, zx, 0, 0, 0);
        const float ei = __builtin_amdgcn_exp2f(-acc[0]);
        const float ef = __builtin_amdgcn_exp2f(-acc[1]);
        const float eg = __builtin_amdgcn_exp2f(-acc[2]);
        const float eo = __builtin_amdgcn_exp2f(-acc[3]);
        const float fv = __builtin_amdgcn_rcpf(1.f + ef);
        const float ig = (1.f - eg) * __builtin_amdgcn_rcpf((1.f + ei) * (1.f + eg));
        c = fmaf(fv, c, ig);
        const float ec = __builtin_amdgcn_exp2f(fminf(c * (-2.f * LOG2E), 40.f));
        const float hv = (1.f - ec) * __builtin_amdgcn_rcpf((1.f + eo) * (1.f + ec));
        h_lds[nxt][L * 40 + hw_off] = f2bf_fast(hv);
        __syncthreads();
    }
#undef LSTM_STEP

    // h(T) lives in buf[0]
    if (tid < 16) {
        float s = b_out[0];
#pragma unroll
        for (int k = 0; k < 32; ++k) s = fmaf(bf2f(h_lds[0][tid * 40 + k]), W_out[k], s);
        out[row0 + tid] = s;
    }
}

extern "C" void kernel_launch(void* const* d_in, const int* in_sizes, int n_in,
                              void* d_out, int out_size, void* d_ws, size_t ws_size,
                              hipStream_t stream) {
    const float* x     = (const float*)d_in[0];
    const float* W_ih  = (const float*)d_in[1];
    const float* W_hh  = (const float*)d_in[2];
    const float* b_ih  = (const float*)d_in[3];
    const float* b_hh  = (const float*)d_in[4];
    const float* W_out = (const float*)d_in[5];
    const float* b_out = (const float*)d_in[6];
    float* out = (float*)d_out;

    const int B = in_sizes[0] / (T_LEN * 8);  // 4096
    const int tiles = B / 16;                 // 256 blocks, one per CU
    lstm_kernel<<<tiles, 512, 0, stream>>>(x, W_ih, W_hh, b_ih, b_hh, W_out, b_out, out);
}

// Round 10
// 139.740 us; speedup vs baseline: 1.3107x; 1.0121x over previous
//
#include <hip/hip_runtime.h>

// LSTM: B=4096, T=256, I=8, H=32, O=1, fp32 in/out, bf16 MFMA compute.
// R14 = R13 with the x(t+2) ds_read moved to the step TAIL (after act and
// h-write) + raw-barrier mechanics so it stays in flight across the step
// boundary. R13's null isolated the mechanism: moving the CONSUMER to regs
// didn't help because the ds_read still issued in the post-barrier burst
// (16 b128/CU hit the shared LDS pipe at once; in-order DS returns make the
// hfrag MFMA wait the full queue). R14 halves the burst to 8 b128: the
// xnext read issues while the LDS pipe is idle (act phase) and its latency
// drains during the barrier. In-loop barrier = ds_write h; ds_read xnext;
// s_waitcnt lgkmcnt(1); s_barrier  — lgkmcnt(1) + per-wave in-order DS
// retirement proves the h-write AND the earlier hfrag read completed, while
// the x-read (last issued) may remain outstanding. One-time full drain
// (lgkmcnt(0)+barrier) before the restage closes the cross-wave WAR on xl.
// Structure log: R8 2 blk/CU=950 cyc/step; R9 4-wave 2j/lane=775; R10
// global-x=1220; R12 2 tiles/blk=533/pair but half CUs idle; R7/R11/R13=700.
// 256 blocks (1/CU) x 8 waves; wave w owns j=4w+q via weight-row perm
// fr -> n = 32*(fr&3)+4w+(fr>>2) (weights = MFMA FIRST operand); lane (q,L)
// acc reg r = gate r at (m=L, j=4w+q); c/h in-register; 8 trans/lane/step.
// x staged in LDS bf16, two 128-step chunks; gate-g rows pre-scaled 2*log2e.

#define T_LEN   256
#define HALF_T  128
#define XSTRIDE 130   // shorts per timestep row (16 L x 8 bf16 + 2 pad)
#define LOG2E   1.4426950408889634f

typedef short bf16x8 __attribute__((ext_vector_type(8)));
typedef float f32x4  __attribute__((ext_vector_type(4)));
typedef unsigned u32x4 __attribute__((ext_vector_type(4)));

static __device__ inline short f2bf_rne(float f) {          // one-time (weights)
    union { float f; unsigned u; } v; v.f = f;
    unsigned u = v.u;
    return (short)((u + 0x7FFFu + ((u >> 16) & 1u)) >> 16);
}
static __device__ inline short f2bf_fast(float f) {         // round-half-up
    union { float f; unsigned u; } v; v.f = f;
    return (short)((v.u + 0x8000u) >> 16);
}
static __device__ inline unsigned pack_bf2(float a, float b) {  // low=a, high=b
    union { float f; unsigned u; } x, y; x.f = a; y.f = b;
    return ((x.u + 0x8000u) >> 16) | ((y.u + 0x8000u) & 0xFFFF0000u);
}
static __device__ inline float bf2f(short s) {
    union { unsigned u; float f; } v;
    v.u = ((unsigned)(unsigned short)s) << 16;
    return v.f;
}

__global__ __launch_bounds__(512, 2) void lstm_kernel(
    const float* __restrict__ x, const float* __restrict__ W_ih,
    const float* __restrict__ W_hh, const float* __restrict__ b_ih,
    const float* __restrict__ b_hh, const float* __restrict__ W_out,
    const float* __restrict__ b_out, float* __restrict__ out)
{
    // x chunk: [t_local(0..127)][L(0..15)][8] bf16 (conflict-free: dword
    // stride 65/t, 4/L; loop reads are 4-lane broadcasts of 16 addresses)
    __shared__ __attribute__((aligned(16))) short xl[HALF_T * XSTRIDE];
    // h double buffer: [buf][m(0..15)][k(0..31)] bf16, row stride 40 shorts
    __shared__ __attribute__((aligned(16))) short h_lds[2][16 * 40];

    const int tid  = threadIdx.x;
    const int w    = tid >> 6;        // wave 0..7 -> owns j = 4w + q
    const int lane = tid & 63;
    const int L    = lane & 15;       // batch row within tile / frag row
    const int q    = lane >> 4;       // quad
    const int row0 = blockIdx.x * 16;
    const float4* xv = (const float4*)x;

    // ---- one-time: weight fragments (FIRST-operand layout [row=L][k=8q+j]) ----
    // row fr=L holds W row n = 32*(L&3) + 4w + (L>>2); gate = L&3,
    // scaled by log2e (gate-g rows: 2*log2e, folding tanh's factor 2).
    const int   n  = 32 * (L & 3) + 4 * w + (L >> 2);
    const float sc = ((L & 3) == 2 ? 2.f * LOG2E : LOG2E);
    bf16x8 whh_f, wih_f = (bf16x8){0,0,0,0,0,0,0,0};
    {
        const float* src = W_hh + n * 32 + q * 8;
#pragma unroll
        for (int j = 0; j < 8; ++j) whh_f[j] = f2bf_rne(src[j] * sc);
        if (q == 0) {                              // only k=0..7 exist (I=8)
            const float* s2 = W_ih + n * 8;
#pragma unroll
            for (int j = 0; j < 8; ++j) wih_f[j] = f2bf_rne(s2[j] * sc);
        }
    }
    // bias in C-layout: reg r -> row fr=4q+r -> n_r = 32r + 4w + q
    f32x4 bias;
#pragma unroll
    for (int r = 0; r < 4; ++r) {
        const int   nr = 32 * r + 4 * w + q;
        const float sr = (r == 2 ? 2.f * LOG2E : LOG2E);
        bias[r] = (b_ih[nr] + b_hh[nr]) * sr;
    }

    // zero h(0) buffer
    for (int i = tid; i < 16 * 40; i += 512) h_lds[0][i] = 0;

    // ---- stage chunk 0 (t in [0,128)) into xl ----
    // idx = tid + 512*it: L2 = idx>>7, tl = idx&127; 32 B/lane coalesced.
#pragma unroll
    for (int it = 0; it < 4; ++it) {
        const int idx = tid + (it << 9);
        const int L2  = idx >> 7;
        const int tl  = idx & (HALF_T - 1);
        const float4* srcp = xv + ((size_t)(row0 + L2) * T_LEN + tl) * 2;
        const float4 a = srcp[0], b = srcp[1];
        u32x4 u;
        u[0] = pack_bf2(a.x, a.y); u[1] = pack_bf2(a.z, a.w);
        u[2] = pack_bf2(b.x, b.y); u[3] = pack_bf2(b.z, b.w);
        *(u32x4*)(&xl[tl * XSTRIDE + L2 * 8]) = u;
    }
    __syncthreads();

    // zx(0) from x(0); prime the x register pipeline with x(1)
    f32x4 zx;
    bf16x8 xcur;
    {
        const bf16x8 xf0 = *(const bf16x8*)(&xl[L * 8]);
        zx   = __builtin_amdgcn_mfma_f32_16x16x32_bf16(wih_f, xf0, bias, 0, 0, 0);
        xcur = *(const bf16x8*)(&xl[1 * XSTRIDE + L * 8]);     // x(1)
    }

    float c = 0.f;
    const int hw_off = 4 * w + q;      // this lane's j

    // One step: read h(t) (chain), MFMA, zx from reg-x(t+1), act, write
    // h(t+1); THEN read x(t+2) into xcur (LDS pipe idle here), then
    // lgkmcnt(1)+s_barrier: h-write proven complete (in-order DS, x-read
    // was issued last), x-read latency drains across the barrier.
#define LSTM_STEP(T_, TN2_)                                                     \
    {                                                                           \
        const int par = (T_) & 1, nxt = par ^ 1;                                \
        const bf16x8 hfrag = *(const bf16x8*)(&h_lds[par][L * 40 + q * 8]);     \
        const f32x4 acc =                                                       \
            __builtin_amdgcn_mfma_f32_16x16x32_bf16(whh_f, hfrag, zx, 0, 0, 0); \
        zx = __builtin_amdgcn_mfma_f32_16x16x32_bf16(wih_f, xcur, bias, 0, 0, 0);\
        const float ei = __builtin_amdgcn_exp2f(-acc[0]);                       \
        const float ef = __builtin_amdgcn_exp2f(-acc[1]);                       \
        const float eg = __builtin_amdgcn_exp2f(-acc[2]);                       \
        const float eo = __builtin_amdgcn_exp2f(-acc[3]);                       \
        const float fv = __builtin_amdgcn_rcpf(1.f + ef);                       \
        const float ig = (1.f - eg) * __builtin_amdgcn_rcpf((1.f + ei) * (1.f + eg)); \
        c = fmaf(fv, c, ig);                                                    \
        const float ec = __builtin_amdgcn_exp2f(fminf(c * (-2.f * LOG2E), 40.f));\
        const float hv = (1.f - ec) * __builtin_amdgcn_rcpf((1.f + eo) * (1.f + ec)); \
        h_lds[nxt][L * 40 + hw_off] = f2bf_fast(hv);                            \
        __builtin_amdgcn_sched_barrier(0);  /* pin: write BEFORE read */        \
        xcur = *(const bf16x8*)(                                                \
            &xl[((TN2_) & (HALF_T - 1)) * XSTRIDE + L * 8]);                    \
        __builtin_amdgcn_sched_barrier(0);  /* pin: read stays at tail */       \
        asm volatile("s_waitcnt lgkmcnt(1)" ::: "memory");                      \
        __builtin_amdgcn_s_barrier();                                           \
        __builtin_amdgcn_sched_barrier(0);  /* no hoist above barrier */        \
    }

    // ---- first phase: t = 0..125; x(t+2) slots 2..127 all in chunk 0 ----
#pragma unroll 2
    for (int t = 0; t < HALF_T - 2; ++t) LSTM_STEP(t, t + 2)

    // ---- full drain before restage: every wave's outstanding x-read must
    //      complete before ANY wave overwrites xl (cross-wave WAR). ----
    asm volatile("s_waitcnt lgkmcnt(0)" ::: "memory");
    __builtin_amdgcn_s_barrier();
    __builtin_amdgcn_sched_barrier(0);

    // ---- restage chunk 1 (t in [128,256)); x(126),x(127) live in regs ----
#pragma unroll
    for (int it = 0; it < 4; ++it) {
        const int idx = tid + (it << 9);
        const int L2  = idx >> 7;
        const int tl  = idx & (HALF_T - 1);
        const float4* srcp = xv + ((size_t)(row0 + L2) * T_LEN + HALF_T + tl) * 2;
        const float4 a = srcp[0], b = srcp[1];
        u32x4 u;
        u[0] = pack_bf2(a.x, a.y); u[1] = pack_bf2(a.z, a.w);
        u[2] = pack_bf2(b.x, b.y); u[3] = pack_bf2(b.z, b.w);
        *(u32x4*)(&xl[tl * XSTRIDE + L2 * 8]) = u;
    }
    __syncthreads();   // one-time vm+lgkm drain; loop stays vm-free

    // ---- second phase: t = 126..254; x(t+2) slots (t+2)&127 in chunk 1,
    //      clamped at 255 (t=254 re-reads x(255), dead but harmless) ----
#pragma unroll 2
    for (int t = HALF_T - 2; t < T_LEN - 1; ++t)
        LSTM_STEP(t, (t + 2 > T_LEN - 1 ? T_LEN - 1 : t + 2))

    // ---- peeled t = 255: no xfrag/zx (dead), store h(T) into buf 0 ----
    {
        const int par = (T_LEN - 1) & 1, nxt = par ^ 1;   // 1 -> 0
        const bf16x8 hfrag = *(const bf16x8*)(&h_lds[par][L * 40 + q * 8]);
        const f32x4 acc =
            __builtin_amdgcn_mfma_f32_16x16x32_bf16(whh_f, hfrag, zx, 0, 0, 0);
        const float ei = __builtin_amdgcn_exp2f(-acc[0]);
        const float ef = __builtin_amdgcn_exp2f(-acc[1]);
        const float eg = __builtin_amdgcn_exp2f(-acc[2]);
        const float eo = __builtin_amdgcn_exp2f(-acc[3]);
        const float fv = __builtin_amdgcn_rcpf(1.f + ef);
        const float ig = (1.f - eg) * __builtin_amdgcn_rcpf((1.f + ei) * (1.f + eg));
        c = fmaf(fv, c, ig);
        const float ec = __builtin_amdgcn_exp2f(fminf(c * (-2.f * LOG2E), 40.f));
        const float hv = (1.f - ec) * __builtin_amdgcn_rcpf((1.f + eo) * (1.f + ec));
        h_lds[nxt][L * 40 + hw_off] = f2bf_fast(hv);
        __syncthreads();
    }
#undef LSTM_STEP

    // h(T) lives in buf[0]
    if (tid < 16) {
        float s = b_out[0];
#pragma unroll
        for (int k = 0; k < 32; ++k) s = fmaf(bf2f(h_lds[0][tid * 40 + k]), W_out[k], s);
        out[row0 + tid] = s;
    }
}

extern "C" void kernel_launch(void* const* d_in, const int* in_sizes, int n_in,
                              void* d_out, int out_size, void* d_ws, size_t ws_size,
                              hipStream_t stream) {
    const float* x     = (const float*)d_in[0];
    const float* W_ih  = (const float*)d_in[1];
    const float* W_hh  = (const float*)d_in[2];
    const float* b_ih  = (const float*)d_in[3];
    const float* b_hh  = (const float*)d_in[4];
    const float* W_out = (const float*)d_in[5];
    const float* b_out = (const float*)d_in[6];
    float* out = (float*)d_out;

    const int B = in_sizes[0] / (T_LEN * 8);  // 4096
    const int tiles = B / 16;                 // 256 blocks, one per CU
    lstm_kernel<<<tiles, 512, 0, stream>>>(x, W_ih, W_hh, b_ih, b_hh, W_out, b_out, out);
}